// Round 17
// baseline (568.432 us; speedup 1.0000x reference)
//
#include <hip/hip_runtime.h>
#include <hip/hip_bf16.h>
#include <hip/hip_fp16.h>
#include <math.h>

#define N_NODES 50000
#define N_EDGES 800000
#define E_TOT   (N_EDGES + N_NODES)
#define F_IN    64
#define HIDDEN  128
#define HEADS   4
#define OUT_DIM 256
#define N_GRAPHS 1024
#define BN_EPS  1e-5f
#define SLOPE   0.2f

#define SCAN_TILE 2048
#define N_TILES   ((N_NODES + SCAN_TILE - 1) / SCAN_TILE)   // 25
#define POOL_NODES 128
#define SCATTER_BLOCKS ((E_TOT + 1023) / 1024)              // 831 (4 edges/thread)
#define GEMM_BLOCKS    ((N_NODES + 63) / 64)                // 782

// ---------------- CSR build ----------------

__global__ void hist_kernel(const int* __restrict__ ei, int* __restrict__ deg) {
    int base = blockIdx.x * blockDim.x * 4 + threadIdx.x;
    #pragma unroll
    for (int u = 0; u < 4; ++u) {
        int i = base + u * 256;
        if (i < E_TOT) {
            int d = (i < N_EDGES) ? ei[N_EDGES + i] : (i - N_EDGES);
            atomicAdd(&deg[d], 1);
        }
    }
}

__global__ void scan_partial_kernel(const int* __restrict__ deg, int* __restrict__ tile_sums) {
    __shared__ int wsum[4];
    int tile = blockIdx.x;
    int tid = threadIdx.x;
    int base = tile * SCAN_TILE + tid * 8;
    int s = 0;
    #pragma unroll
    for (int k = 0; k < 8; ++k) {
        int i = base + k;
        if (i < N_NODES) s += deg[i];
    }
    int lane = tid & 63;
    for (int off = 1; off < 64; off <<= 1) s += __shfl_xor(s, off, 64);
    if (lane == 0) wsum[tid >> 6] = s;
    __syncthreads();
    if (tid == 0) tile_sums[tile] = wsum[0] + wsum[1] + wsum[2] + wsum[3];
}

__global__ void scan_tilesums_kernel(const int* __restrict__ tile_sums, int* __restrict__ tile_off) {
    if (threadIdx.x == 0) {
        int acc = 0;
        for (int t = 0; t < N_TILES; ++t) { tile_off[t] = acc; acc += tile_sums[t]; }
    }
}

__global__ void scan_apply_kernel(const int* __restrict__ deg, const int* __restrict__ tile_off,
                                  int* __restrict__ row_start) {
    __shared__ int wsum[4];
    int tile = blockIdx.x;
    int tid = threadIdx.x;
    int lane = tid & 63;
    int wid = tid >> 6;
    int base = tile * SCAN_TILE + tid * 8;
    int v[8];
    int tsum = 0;
    #pragma unroll
    for (int k = 0; k < 8; ++k) {
        int i = base + k;
        v[k] = (i < N_NODES) ? deg[i] : 0;
        tsum += v[k];
    }
    int sc = tsum;
    for (int off = 1; off < 64; off <<= 1) {
        int t = __shfl_up(sc, off, 64);
        if (lane >= off) sc += t;
    }
    if (lane == 63) wsum[wid] = sc;
    __syncthreads();
    int woff = 0;
    for (int w = 0; w < 4; ++w) woff += (w < wid) ? wsum[w] : 0;
    __syncthreads();
    int toff = tile_off[tile] + woff + (sc - tsum);
    #pragma unroll
    for (int k = 0; k < 8; ++k) {
        int i = base + k;
        if (i < N_NODES) row_start[i] = toff;
        toff += v[k];
    }
    if (tile == 0 && tid == 0) row_start[N_NODES] = E_TOT;
}

// ---------------- device bodies (for fusion) ----------------

__device__ __forceinline__ void scatter_body(const int* __restrict__ ei,
                                             const int* __restrict__ row_start,
                                             int* __restrict__ cursor,
                                             unsigned short* __restrict__ csr_src,
                                             int bid) {
    int base = bid * 1024 + threadIdx.x;
    int s[4], d[4];
    bool ok[4];
    #pragma unroll
    for (int u = 0; u < 4; ++u) {
        int i = base + u * 256;
        ok[u] = i < E_TOT;
        if (ok[u]) {
            if (i < N_EDGES) { s[u] = ei[i]; d[u] = ei[N_EDGES + i]; }
            else             { s[u] = i - N_EDGES; d[u] = s[u]; }
        }
    }
    int pos[4];
    #pragma unroll
    for (int u = 0; u < 4; ++u)
        if (ok[u]) pos[u] = atomicAdd(&cursor[d[u]], 1);
    #pragma unroll
    for (int u = 0; u < 4; ++u)
        if (ok[u]) csr_src[row_start[d[u]] + pos[u]] = (unsigned short)s[u];
}

// XHALF: X is fp16 (layer-2 input B); else f32 (layer-1 input x)
template<int FIN, bool XHALF>
__device__ __forceinline__ void gemm_att_body(
        const void* __restrict__ Xv, const float* __restrict__ W,
        const float* __restrict__ a_src, const float* __restrict__ a_dst,
        __half* __restrict__ H, float* __restrict__ es, float* __restrict__ ed,
        int bid, float* Wl) {
    int tid = threadIdx.x;
    for (int i = tid * 4; i < FIN * HIDDEN; i += 256 * 4) {
        *reinterpret_cast<float4*>(&Wl[i]) = *reinterpret_cast<const float4*>(&W[i]);
    }
    __syncthreads();

    int cg = tid & 15;
    int np = tid >> 4;
    int nb = bid * 64 + np * 4;
    int j0 = cg * 8;

    bool ok[4];
    size_t rowb[4];
    #pragma unroll
    for (int t = 0; t < 4; ++t) {
        ok[t] = (nb + t) < N_NODES;
        rowb[t] = (size_t)(ok[t] ? nb + t : 0) * FIN;
    }
    float acc[4][8];
    #pragma unroll
    for (int t = 0; t < 4; ++t)
        #pragma unroll
        for (int c = 0; c < 8; ++c) acc[t][c] = 0.f;

    for (int k = 0; k < FIN; k += 4) {
        float4 xa[4];
        if constexpr (XHALF) {
            const __half* xb = (const __half*)Xv;
            #pragma unroll
            for (int t = 0; t < 4; ++t) {
                union { float2 f2; __half2 h2[2]; } u;
                u.f2 = *reinterpret_cast<const float2*>(xb + rowb[t] + k);
                float2 a = __half22float2(u.h2[0]);
                float2 c = __half22float2(u.h2[1]);
                xa[t] = make_float4(a.x, a.y, c.x, c.y);
            }
        } else {
            const float* xb = (const float*)Xv;
            #pragma unroll
            for (int t = 0; t < 4; ++t)
                xa[t] = *reinterpret_cast<const float4*>(xb + rowb[t] + k);
        }
        #pragma unroll
        for (int kk = 0; kk < 4; ++kk) {
            const float4 wA = *reinterpret_cast<const float4*>(&Wl[(k + kk) * HIDDEN + j0]);
            const float4 wB = *reinterpret_cast<const float4*>(&Wl[(k + kk) * HIDDEN + j0 + 4]);
            #pragma unroll
            for (int t = 0; t < 4; ++t) {
                float xv = (kk == 0) ? xa[t].x : (kk == 1) ? xa[t].y : (kk == 2) ? xa[t].z : xa[t].w;
                acc[t][0] += xv * wA.x; acc[t][1] += xv * wA.y;
                acc[t][2] += xv * wA.z; acc[t][3] += xv * wA.w;
                acc[t][4] += xv * wB.x; acc[t][5] += xv * wB.y;
                acc[t][6] += xv * wB.z; acc[t][7] += xv * wB.w;
            }
        }
    }

    #pragma unroll
    for (int t = 0; t < 4; ++t) {
        int n = nb + t;
        if (ok[t]) {
            union { __half2 h2[4]; float4 f4; } pk;
            pk.h2[0] = __floats2half2_rn(acc[t][0], acc[t][1]);
            pk.h2[1] = __floats2half2_rn(acc[t][2], acc[t][3]);
            pk.h2[2] = __floats2half2_rn(acc[t][4], acc[t][5]);
            pk.h2[3] = __floats2half2_rn(acc[t][6], acc[t][7]);
            *reinterpret_cast<float4*>(H + (size_t)n * HIDDEN + j0) = pk.f4;
        }
        float vs = 0.f, vd = 0.f;
        #pragma unroll
        for (int c = 0; c < 8; ++c) {
            vs += acc[t][c] * a_src[j0 + c];
            vd += acc[t][c] * a_dst[j0 + c];
        }
        vs += __shfl_xor(vs, 1, 64); vs += __shfl_xor(vs, 2, 64);
        vd += __shfl_xor(vd, 1, 64); vd += __shfl_xor(vd, 2, 64);
        if ((cg & 3) == 0 && ok[t]) {
            int h = cg >> 2;
            es[n * HEADS + h] = vs;
            ed[n * HEADS + h] = vd;
        }
    }
}

// fused: scatter blocks backfilled with layer-1 GEMM blocks (independent work)
__global__ __launch_bounds__(256) void scatter_gemm1_kernel(
        const int* __restrict__ ei, const int* __restrict__ row_start,
        int* __restrict__ cursor, unsigned short* __restrict__ csr_src,
        const float* __restrict__ X, const float* __restrict__ W,
        const float* __restrict__ a_src, const float* __restrict__ a_dst,
        __half* __restrict__ H, float* __restrict__ es, float* __restrict__ ed) {
    __shared__ float Wl[F_IN * HIDDEN];
    int bid = blockIdx.x;
    if (bid < SCATTER_BLOCKS) {
        scatter_body(ei, row_start, cursor, csr_src, bid);
    } else {
        gemm_att_body<F_IN, false>(X, W, a_src, a_dst, H, es, ed, bid - SCATTER_BLOCKS, Wl);
    }
}

// standalone layer-2 GEMM (fp16 input B)
__global__ __launch_bounds__(256) void gemm_att2_kernel(
        const __half* __restrict__ X, const float* __restrict__ W,
        const float* __restrict__ a_src, const float* __restrict__ a_dst,
        __half* __restrict__ H, float* __restrict__ es, float* __restrict__ ed) {
    __shared__ float Wl[HIDDEN * HIDDEN];
    gemm_att_body<HIDDEN, true>(X, W, a_src, a_dst, H, es, ed, blockIdx.x, Wl);
}

// ---------------- per-node GAT aggregation (1 wave / node, fp16 gather, 8x unroll, fp16 out) ----------------
__global__ void gat_aggregate_kernel(const __half* __restrict__ H, const float* __restrict__ es,
                                     const float* __restrict__ ed, const int* __restrict__ row_start,
                                     const unsigned short* __restrict__ csr_src,
                                     const float* __restrict__ bias,
                                     __half* __restrict__ out) {
    int lane = threadIdx.x & 63;
    int n = blockIdx.x * 4 + (threadIdx.x >> 6);
    if (n >= N_NODES) return;
    int hid = lane >> 4;
    float edn = ed[n * HEADS + hid];
    int k0 = row_start[n], k1 = row_start[n + 1];
    const __half2* Hp = reinterpret_cast<const __half2*>(H);
    float dsum = 0.f, accx = 0.f, accy = 0.f;
    int k = k0;
    for (; k + 7 < k1; k += 8) {
        int s[8]; float e[8]; __half2 hh[8];
        #pragma unroll
        for (int u = 0; u < 8; ++u) s[u] = csr_src[k + u];
        #pragma unroll
        for (int u = 0; u < 8; ++u) e[u] = es[s[u] * HEADS + hid];
        #pragma unroll
        for (int u = 0; u < 8; ++u) hh[u] = Hp[(size_t)s[u] * (HIDDEN / 2) + lane];
        #pragma unroll
        for (int u = 0; u < 8; ++u) {
            float ee = e[u] + edn;
            ee = fmaxf(ee, SLOPE * ee);
            float ex = __expf(ee);
            float2 f = __half22float2(hh[u]);
            dsum += ex;
            accx += ex * f.x;
            accy += ex * f.y;
        }
    }
    for (; k < k1; ++k) {
        int s0 = csr_src[k];
        float e0 = es[s0 * HEADS + hid] + edn;
        __half2 h0 = Hp[(size_t)s0 * (HIDDEN / 2) + lane];
        e0 = fmaxf(e0, SLOPE * e0);
        float ex0 = __expf(e0);
        float2 f0 = __half22float2(h0);
        dsum += ex0;
        accx += ex0 * f0.x;
        accy += ex0 * f0.y;
    }
    float inv = 1.f / (dsum + 1e-16f);
    int j = 2 * lane;
    reinterpret_cast<__half2*>(out)[(size_t)n * (HIDDEN / 2) + lane] =
        __floats2half2_rn(accx * inv + bias[j], accy * inv + bias[j + 1]);
}

// ---------------- BatchNorm (2-pass) + ELU, fp16 B ----------------
__global__ void bn_stats_kernel(const __half* __restrict__ X, float* __restrict__ stats) {
    int cp = threadIdx.x & 63;           // channel pair (channels 2cp, 2cp+1)
    int rg = threadIdx.x >> 6;           // 0..3
    const __half2* Xp = reinterpret_cast<const __half2*>(X);
    float sx = 0.f, sy = 0.f, s2x = 0.f, s2y = 0.f;
    for (int n = blockIdx.x * 4 + rg; n < N_NODES; n += gridDim.x * 4) {
        float2 f = __half22float2(Xp[(size_t)n * (HIDDEN / 2) + cp]);
        sx += f.x; sy += f.y;
        s2x += f.x * f.x; s2y += f.y * f.y;
    }
    atomicAdd(&stats[2 * cp], sx);
    atomicAdd(&stats[2 * cp + 1], sy);
    atomicAdd(&stats[HIDDEN + 2 * cp], s2x);
    atomicAdd(&stats[HIDDEN + 2 * cp + 1], s2y);
}

__global__ void bn_apply_kernel(__half* __restrict__ X, const float* __restrict__ stats,
                                const float* __restrict__ g, const float* __restrict__ b) {
    const float invN = 1.f / (float)N_NODES;
    __half2* Xp = reinterpret_cast<__half2*>(X);
    int i = blockIdx.x * blockDim.x + threadIdx.x;
    const int total = N_NODES * (HIDDEN / 2);
    for (; i < total; i += gridDim.x * blockDim.x) {
        int cp = i & 63;
        int c0 = 2 * cp, c1 = c0 + 1;
        float mu0 = stats[c0] * invN, mu1 = stats[c1] * invN;
        float var0 = stats[HIDDEN + c0] * invN - mu0 * mu0;
        float var1 = stats[HIDDEN + c1] * invN - mu1 * mu1;
        float2 f = __half22float2(Xp[i]);
        float v0 = (f.x - mu0) * rsqrtf(var0 + BN_EPS) * g[c0] + b[c0];
        float v1 = (f.y - mu1) * rsqrtf(var1 + BN_EPS) * g[c1] + b[c1];
        v0 = (v0 > 0.f) ? v0 : expm1f(v0);
        v1 = (v1 > 0.f) ? v1 : expm1f(v1);
        Xp[i] = __floats2half2_rn(v0, v1);
    }
}

// layer-2: BN+ELU fused into pooling, exploiting SORTED batch; fp16 input
__global__ __launch_bounds__(256) void bn_apply_pool_kernel(
        const __half* __restrict__ X, const float* __restrict__ stats,
        const float* __restrict__ g, const float* __restrict__ b,
        const int* __restrict__ batch,
        float* __restrict__ psum, float* __restrict__ pcnt) {
    const float invN = 1.f / (float)N_NODES;
    int cp = threadIdx.x & 63;           // channel pair
    int h = threadIdx.x >> 6;            // 0..3 node quarter
    int n0 = blockIdx.x * POOL_NODES + h * (POOL_NODES / 4);
    int n1 = n0 + POOL_NODES / 4;
    if (n1 > N_NODES) n1 = N_NODES;
    if (n0 >= n1) return;
    const __half2* Xp = reinterpret_cast<const __half2*>(X);
    int c0 = 2 * cp, c1 = c0 + 1;
    float mu0 = stats[c0] * invN, mu1 = stats[c1] * invN;
    float var0 = stats[HIDDEN + c0] * invN - mu0 * mu0;
    float var1 = stats[HIDDEN + c1] * invN - mu1 * mu1;
    float sc0 = rsqrtf(var0 + BN_EPS) * g[c0];
    float sc1 = rsqrtf(var1 + BN_EPS) * g[c1];
    float sh0 = b[c0] - mu0 * sc0;
    float sh1 = b[c1] - mu1 * sc1;
    int cur = batch[n0];
    float ra0 = 0.f, ra1 = 0.f, rcnt = 0.f;
    for (int n = n0; n < n1; ++n) {
        int gi = batch[n];
        if (gi != cur) {
            atomicAdd(&psum[cur * HIDDEN + c0], ra0);
            atomicAdd(&psum[cur * HIDDEN + c1], ra1);
            if (cp == 0) atomicAdd(&pcnt[cur], rcnt);
            ra0 = 0.f; ra1 = 0.f; rcnt = 0.f; cur = gi;
        }
        float2 f = __half22float2(Xp[(size_t)n * (HIDDEN / 2) + cp]);
        float v0 = f.x * sc0 + sh0;
        float v1 = f.y * sc1 + sh1;
        v0 = (v0 > 0.f) ? v0 : expm1f(v0);
        v1 = (v1 > 0.f) ? v1 : expm1f(v1);
        ra0 += v0; ra1 += v1; rcnt += 1.f;
    }
    atomicAdd(&psum[cur * HIDDEN + c0], ra0);
    atomicAdd(&psum[cur * HIDDEN + c1], ra1);
    if (cp == 0) atomicAdd(&pcnt[cur], rcnt);
}

// ---------------- final linear ----------------
__global__ void final_kernel(const float* __restrict__ psum, const float* __restrict__ pcnt,
                             const float* __restrict__ Wlin, const float* __restrict__ blin,
                             float* __restrict__ out) {
    int idx = blockIdx.x * blockDim.x + threadIdx.x;
    int g = idx >> 8, o = idx & 255;
    float invc = 1.f / fmaxf(pcnt[g], 1.f);
    float acc = blin[o];
    const float* pr = psum + g * HIDDEN;
    for (int j = 0; j < HIDDEN; ++j)
        acc += pr[j] * invc * Wlin[j * OUT_DIM + o];
    out[idx] = acc;
}

// ---------------- launch ----------------

extern "C" void kernel_launch(void* const* d_in, const int* in_sizes, int n_in,
                              void* d_out, int out_size, void* d_ws, size_t ws_size,
                              hipStream_t stream) {
    const float* x    = (const float*)d_in[0];
    const int*   ei   = (const int*)d_in[1];
    const int*   batch= (const int*)d_in[2];
    const float* W1   = (const float*)d_in[3];
    const float* as1  = (const float*)d_in[4];
    const float* ad1  = (const float*)d_in[5];
    const float* b1   = (const float*)d_in[6];
    const float* W2   = (const float*)d_in[7];
    const float* as2  = (const float*)d_in[8];
    const float* ad2  = (const float*)d_in[9];
    const float* b2   = (const float*)d_in[10];
    const float* bn1g = (const float*)d_in[11];
    const float* bn1b = (const float*)d_in[12];
    const float* bn2g = (const float*)d_in[13];
    const float* bn2b = (const float*)d_in[14];
    const float* Wlin = (const float*)d_in[15];
    const float* blin = (const float*)d_in[16];
    float* out = (float*)d_out;

    char* ws = (char*)d_ws;
    const size_t SZ_H = (size_t)N_NODES * HIDDEN * 4;
    __half* A       = (__half*)(ws);                      // fp16 H
    __half* B       = (__half*)(ws + SZ_H);               // fp16 node features
    size_t off = 2 * SZ_H;
    float* es       = (float*)(ws + off); off += (size_t)N_NODES * HEADS * 4;
    float* ed       = (float*)(ws + off); off += (size_t)N_NODES * HEADS * 4;
    int*   row_start= (int*)(ws + off);   off += ((size_t)(N_NODES + 1) * 4 + 511) & ~511ull;
    unsigned short* csr_src = (unsigned short*)(ws + off);
    off += ((size_t)E_TOT * 2 + 511) & ~511ull;
    int*   tile_sums= (int*)(ws + off);   off += ((size_t)N_TILES * 4 + 511) & ~511ull;
    int*   tile_off = (int*)(ws + off);   off += ((size_t)N_TILES * 4 + 511) & ~511ull;
    size_t zoff = off;
    int*   deg      = (int*)(ws + off);   off += (size_t)N_NODES * 4;
    int*   cursor   = (int*)(ws + off);   off += (size_t)N_NODES * 4;
    float* stats1   = (float*)(ws + off); off += 2 * HIDDEN * 4;
    float* stats2   = (float*)(ws + off); off += 2 * HIDDEN * 4;
    float* psum     = (float*)(ws + off); off += (size_t)N_GRAPHS * HIDDEN * 4;
    float* pcnt     = (float*)(ws + off); off += (size_t)N_GRAPHS * 4;
    size_t zbytes = off - zoff;
    (void)ws_size; (void)n_in; (void)in_sizes; (void)out_size;

    hipMemsetAsync(ws + zoff, 0, zbytes, stream);

    const int TB = 256;
    const int pgrid = (N_NODES + POOL_NODES - 1) / POOL_NODES;

    // CSR build prefix
    hist_kernel<<<SCATTER_BLOCKS, TB, 0, stream>>>(ei, deg);
    scan_partial_kernel<<<N_TILES, TB, 0, stream>>>(deg, tile_sums);
    scan_tilesums_kernel<<<1, 64, 0, stream>>>(tile_sums, tile_off);
    scan_apply_kernel<<<N_TILES, TB, 0, stream>>>(deg, tile_off, row_start);

    // ---- fused: scatter (CSR) || layer-1 GEMM (independent) ----
    scatter_gemm1_kernel<<<SCATTER_BLOCKS + GEMM_BLOCKS, TB, 0, stream>>>(
        ei, row_start, cursor, csr_src, x, W1, as1, ad1, A, es, ed);

    // ---- layer 1 rest ----
    gat_aggregate_kernel<<<N_NODES / 4, TB, 0, stream>>>(A, es, ed, row_start, csr_src, b1, B);
    bn_stats_kernel<<<512, TB, 0, stream>>>(B, stats1);
    bn_apply_kernel<<<2048, TB, 0, stream>>>(B, stats1, bn1g, bn1b);

    // ---- layer 2 ----
    gemm_att2_kernel<<<GEMM_BLOCKS, TB, 0, stream>>>(B, W2, as2, ad2, A, es, ed);
    gat_aggregate_kernel<<<N_NODES / 4, TB, 0, stream>>>(A, es, ed, row_start, csr_src, b2, B);
    bn_stats_kernel<<<512, TB, 0, stream>>>(B, stats2);
    bn_apply_pool_kernel<<<pgrid, TB, 0, stream>>>(B, stats2, bn2g, bn2b, batch, psum, pcnt);

    // ---- final linear ----
    final_kernel<<<(N_GRAPHS * OUT_DIM) / TB, TB, 0, stream>>>(psum, pcnt, Wlin, blin, out);
}